// Round 2
// baseline (1003.097 us; speedup 1.0000x reference)
//
#include <hip/hip_runtime.h>
#include <math.h>

#define N_NODES 100000
#define E_EDGES 800000
#define M 4   // nodes per wave

__global__ void build_row_start(const int* __restrict__ edge_dst,
                                int* __restrict__ row_start) {
    int e = blockIdx.x * blockDim.x + threadIdx.x;
    if (e >= E_EDGES) return;
    int d = edge_dst[e];
    int dprev = (e == 0) ? -1 : edge_dst[e - 1];
    for (int n = dprev + 1; n <= d; ++n) row_start[n] = e;
    if (e == E_EDGES - 1) {
        for (int n = d + 1; n <= N_NODES; ++n) row_start[n] = E_EDGES;
    }
}

template<bool USE_RS>
__global__ __launch_bounds__(256) void vae_fused(
    const float* __restrict__ x,
    const int* __restrict__ edge_src,
    const int* __restrict__ edge_dst,
    const float* __restrict__ eps,
    const float* __restrict__ W_agg, const float* __restrict__ b_agg,
    const float* __restrict__ W_fus, const float* __restrict__ b_fus,
    const float* __restrict__ W1,  const float* __restrict__ b1,
    const float* __restrict__ W21, const float* __restrict__ b21,
    const float* __restrict__ W22, const float* __restrict__ b22,
    const float* __restrict__ W3,  const float* __restrict__ b3,
    const float* __restrict__ W4,  const float* __restrict__ b4,
    const int* __restrict__ row_start,
    float* __restrict__ out)
{
    const int wave = (int)((blockIdx.x * blockDim.x + threadIdx.x) >> 6);
    const int lane = (int)(threadIdx.x & 63);
    const int base = wave * M;
    if (base >= N_NODES) return;

    // ---- edge ranges for the M nodes ----
    int rs[M + 1];
    if (USE_RS) {
        #pragma unroll
        for (int m = 0; m <= M; ++m) rs[m] = row_start[base + m];
    } else {
        #pragma unroll
        for (int m = 0; m <= M; ++m) {
            int lo = 0, hi = E_EDGES, tgt = base + m;
            while (lo < hi) { int mid = (lo + hi) >> 1; if (edge_dst[mid] < tgt) lo = mid + 1; else hi = mid; }
            rs[m] = lo;
        }
    }

    // ---- segment mean ----
    float avg[M];
    #pragma unroll
    for (int m = 0; m < M; ++m) {
        float sum = 0.0f;
        for (int e = rs[m]; e < rs[m + 1]; ++e)
            sum += x[(long)edge_src[e] * 64 + lane];
        const float c = (float)(rs[m + 1] - rs[m]);
        avg[m] = sum / fmaxf(c, 1.0f);
    }

    // ---- self features ----
    float xv[M];
    #pragma unroll
    for (int m = 0; m < M; ++m) xv[m] = x[(long)(base + m) * 64 + lane];

    // ---- ne = relu(avg @ W_agg + b_agg) ----
    float ne[M];
    { const float b = b_agg[lane];
      #pragma unroll
      for (int m = 0; m < M; ++m) ne[m] = b; }
    #pragma unroll
    for (int k = 0; k < 64; ++k) {
        const float w = W_agg[k * 64 + lane];
        #pragma unroll
        for (int m = 0; m < M; ++m)
            ne[m] = fmaf(__shfl(avg[m], k, 64), w, ne[m]);
    }
    #pragma unroll
    for (int m = 0; m < M; ++m) ne[m] = fmaxf(ne[m], 0.0f);

    // ---- xf = relu([x, ne] @ W_fus + b_fus) ----
    float xf[M];
    { const float b = b_fus[lane];
      #pragma unroll
      for (int m = 0; m < M; ++m) xf[m] = b; }
    #pragma unroll
    for (int k = 0; k < 64; ++k) {
        const float w = W_fus[k * 64 + lane];
        #pragma unroll
        for (int m = 0; m < M; ++m)
            xf[m] = fmaf(__shfl(xv[m], k, 64), w, xf[m]);
    }
    #pragma unroll
    for (int k = 0; k < 64; ++k) {
        const float w = W_fus[(64 + k) * 64 + lane];
        #pragma unroll
        for (int m = 0; m < M; ++m)
            xf[m] = fmaf(__shfl(ne[m], k, 64), w, xf[m]);
    }
    #pragma unroll
    for (int m = 0; m < M; ++m) xf[m] = fmaxf(xf[m], 0.0f);

    // ---- h1 = relu(xf @ W1 + b1) ----
    float h1[M];
    { const float b = b1[lane];
      #pragma unroll
      for (int m = 0; m < M; ++m) h1[m] = b; }
    #pragma unroll
    for (int k = 0; k < 64; ++k) {
        const float w = W1[k * 64 + lane];
        #pragma unroll
        for (int m = 0; m < M; ++m)
            h1[m] = fmaf(__shfl(xf[m], k, 64), w, h1[m]);
    }
    #pragma unroll
    for (int m = 0; m < M; ++m) h1[m] = fmaxf(h1[m], 0.0f);

    // ---- mu, logvar (16-wide, replicated across the 4 lane groups) ----
    const int j = lane & 15;
    float mu[M], lv[M];
    { const float bm = b21[j], bl = b22[j];
      #pragma unroll
      for (int m = 0; m < M; ++m) { mu[m] = bm; lv[m] = bl; } }
    #pragma unroll
    for (int k = 0; k < 64; ++k) {
        const float w21 = W21[k * 16 + j];
        const float w22 = W22[k * 16 + j];
        #pragma unroll
        for (int m = 0; m < M; ++m) {
            const float a = __shfl(h1[m], k, 64);
            mu[m] = fmaf(a, w21, mu[m]);
            lv[m] = fmaf(a, w22, lv[m]);
        }
    }

    // ---- z = mu + eps * exp(0.5*logvar) ----
    float z[M];
    #pragma unroll
    for (int m = 0; m < M; ++m)
        z[m] = mu[m] + eps[(long)(base + m) * 16 + j] * expf(0.5f * lv[m]);

    // ---- h3 = relu(z @ W3 + b3) ----
    float h3[M];
    { const float b = b3[lane];
      #pragma unroll
      for (int m = 0; m < M; ++m) h3[m] = b; }
    #pragma unroll
    for (int k = 0; k < 16; ++k) {
        const float w = W3[k * 64 + lane];
        #pragma unroll
        for (int m = 0; m < M; ++m)
            h3[m] = fmaf(__shfl(z[m], k, 64), w, h3[m]);
    }
    #pragma unroll
    for (int m = 0; m < M; ++m) h3[m] = fmaxf(h3[m], 0.0f);

    // ---- recon = sigmoid(h3 @ W4 + b4) ----
    float pre[M];
    { const float b = b4[lane];
      #pragma unroll
      for (int m = 0; m < M; ++m) pre[m] = b; }
    #pragma unroll
    for (int k = 0; k < 64; ++k) {
        const float w = W4[k * 64 + lane];
        #pragma unroll
        for (int m = 0; m < M; ++m)
            pre[m] = fmaf(__shfl(h3[m], k, 64), w, pre[m]);
    }

    // ---- outputs: recon [N,64] | mu [N,16] | logvar [N,16] ----
    #pragma unroll
    for (int m = 0; m < M; ++m) {
        const int node = base + m;
        out[(long)node * 64 + lane] = 1.0f / (1.0f + expf(-pre[m]));
        if (lane < 16) {
            out[(long)N_NODES * 64 + (long)node * 16 + j] = mu[m];
            out[(long)N_NODES * 64 + (long)N_NODES * 16 + (long)node * 16 + j] = lv[m];
        }
    }
}

extern "C" void kernel_launch(void* const* d_in, const int* in_sizes, int n_in,
                              void* d_out, int out_size, void* d_ws, size_t ws_size,
                              hipStream_t stream) {
    const float* x        = (const float*)d_in[0];
    const int*   edge_src = (const int*)  d_in[1];
    const int*   edge_dst = (const int*)  d_in[2];
    const float* eps      = (const float*)d_in[3];
    const float* W_agg    = (const float*)d_in[4];
    const float* b_agg    = (const float*)d_in[5];
    const float* W_fus    = (const float*)d_in[6];
    const float* b_fus    = (const float*)d_in[7];
    const float* W1       = (const float*)d_in[8];
    const float* b1       = (const float*)d_in[9];
    const float* W21      = (const float*)d_in[10];
    const float* b21      = (const float*)d_in[11];
    const float* W22      = (const float*)d_in[12];
    const float* b22      = (const float*)d_in[13];
    const float* W3       = (const float*)d_in[14];
    const float* b3       = (const float*)d_in[15];
    const float* W4       = (const float*)d_in[16];
    const float* b4       = (const float*)d_in[17];
    float* out = (float*)d_out;

    const int waves = (N_NODES + M - 1) / M;           // 25000
    const int grid  = (waves * 64 + 255) / 256;        // 6250 blocks

    if (ws_size >= (size_t)(N_NODES + 1) * sizeof(int)) {
        int* row_start = (int*)d_ws;
        build_row_start<<<(E_EDGES + 255) / 256, 256, 0, stream>>>(edge_dst, row_start);
        vae_fused<true><<<grid, 256, 0, stream>>>(x, edge_src, edge_dst, eps,
                                                  W_agg, b_agg, W_fus, b_fus,
                                                  W1, b1, W21, b21, W22, b22,
                                                  W3, b3, W4, b4, row_start, out);
    } else {
        vae_fused<false><<<grid, 256, 0, stream>>>(x, edge_src, edge_dst, eps,
                                                   W_agg, b_agg, W_fus, b_fus,
                                                   W1, b1, W21, b21, W22, b22,
                                                   W3, b3, W4, b4, (const int*)nullptr, out);
    }
}

// Round 3
// 323.194 us; speedup vs baseline: 3.1037x; 3.1037x over previous
//
#include <hip/hip_runtime.h>
#include <math.h>

#define N_NODES 100000
#define E_EDGES 800000
#define M 4            // nodes per wave
#define NGROUPS (N_NODES / M)   // 25000
#define SA 68          // padded stride for K<=64 weight rows (16B aligned, bank-spread)
#define SF 132         // padded stride for K=128
#define S3 20          // padded stride for K=16

__global__ void build_row_start(const int* __restrict__ edge_dst,
                                int* __restrict__ row_start) {
    int e = blockIdx.x * blockDim.x + threadIdx.x;
    if (e >= E_EDGES) return;
    int d = edge_dst[e];
    int dprev = (e == 0) ? -1 : edge_dst[e - 1];
    for (int n = dprev + 1; n <= d; ++n) row_start[n] = e;
    if (e == E_EDGES - 1) {
        for (int n = d + 1; n <= N_NODES; ++n) row_start[n] = E_EDGES;
    }
}

__device__ __forceinline__ float bcast(float v, int l) {
    return __int_as_float(__builtin_amdgcn_readlane(__float_as_int(v), l));
}

template<bool USE_RS>
__global__ __launch_bounds__(1024, 4) void vae_fused(
    const float* __restrict__ x,
    const int* __restrict__ edge_src,
    const int* __restrict__ edge_dst,
    const float* __restrict__ eps,
    const float* __restrict__ W_agg, const float* __restrict__ b_agg,
    const float* __restrict__ W_fus, const float* __restrict__ b_fus,
    const float* __restrict__ W1,  const float* __restrict__ b1,
    const float* __restrict__ W21, const float* __restrict__ b21,
    const float* __restrict__ W22, const float* __restrict__ b22,
    const float* __restrict__ W3,  const float* __restrict__ b3,
    const float* __restrict__ W4,  const float* __restrict__ b4,
    const int* __restrict__ row_start,
    float* __restrict__ out)
{
    __shared__ __align__(16) float s_agg[64 * SA];
    __shared__ __align__(16) float s_fus[64 * SF];
    __shared__ __align__(16) float s_w1 [64 * SA];
    __shared__ __align__(16) float s_w21[16 * SA];
    __shared__ __align__(16) float s_w22[16 * SA];
    __shared__ __align__(16) float s_w3 [64 * S3];
    __shared__ __align__(16) float s_w4 [64 * SA];
    __shared__ float s_b[352];   // agg@0 fus@64 b1@128 b21@192 b22@208 b3@224 b4@288

    const int tid = threadIdx.x;

    // ---- stage weights transposed: s_W[j][k] = W[k][j] ----
    for (int t = tid; t < 64 * 64; t += 1024) s_agg[(t & 63) * SA + (t >> 6)] = W_agg[t];
    for (int t = tid; t < 128 * 64; t += 1024) s_fus[(t & 63) * SF + (t >> 6)] = W_fus[t];
    for (int t = tid; t < 64 * 64; t += 1024) s_w1[(t & 63) * SA + (t >> 6)] = W1[t];
    for (int t = tid; t < 64 * 16; t += 1024) s_w21[(t & 15) * SA + (t >> 4)] = W21[t];
    for (int t = tid; t < 64 * 16; t += 1024) s_w22[(t & 15) * SA + (t >> 4)] = W22[t];
    for (int t = tid; t < 16 * 64; t += 1024) s_w3[(t & 63) * S3 + (t >> 6)] = W3[t];
    for (int t = tid; t < 64 * 64; t += 1024) s_w4[(t & 63) * SA + (t >> 6)] = W4[t];
    if (tid < 64) {
        s_b[tid]       = b_agg[tid];
        s_b[64 + tid]  = b_fus[tid];
        s_b[128 + tid] = b1[tid];
        s_b[224 + tid] = b3[tid];
        s_b[288 + tid] = b4[tid];
    }
    if (tid < 16) {
        s_b[192 + tid] = b21[tid];
        s_b[208 + tid] = b22[tid];
    }
    __syncthreads();

    const int lane  = tid & 63;
    const int wid   = tid >> 6;
    const int gwave = blockIdx.x * 16 + wid;
    const int nwav  = gridDim.x * 16;
    const int j     = lane & 15;

    for (int g = gwave; g < NGROUPS; g += nwav) {
        const int base = g * M;

        // ---- edge ranges ----
        int rs[M + 1];
        if (USE_RS) {
            #pragma unroll
            for (int m = 0; m <= M; ++m) rs[m] = row_start[base + m];
        } else {
            #pragma unroll
            for (int m = 0; m <= M; ++m) {
                int lo = 0, hi = E_EDGES, tgt = base + m;
                while (lo < hi) { int mid = (lo + hi) >> 1; if (edge_dst[mid] < tgt) lo = mid + 1; else hi = mid; }
                rs[m] = lo;
            }
        }

        // ---- segment mean + self feature ----
        float avg[M], xv[M];
        #pragma unroll
        for (int m = 0; m < M; ++m) {
            float sum = 0.0f;
            for (int e = rs[m]; e < rs[m + 1]; ++e)
                sum += x[(long)edge_src[e] * 64 + lane];
            avg[m] = sum / fmaxf((float)(rs[m + 1] - rs[m]), 1.0f);
            xv[m] = x[(long)(base + m) * 64 + lane];
        }

        // ---- ne = relu(avg @ W_agg + b_agg) ----
        float ne[M];
        #pragma unroll
        for (int m = 0; m < M; ++m) ne[m] = s_b[lane];
        #pragma unroll 4
        for (int k4 = 0; k4 < 64; k4 += 4) {
            const float4 w = *(const float4*)&s_agg[lane * SA + k4];
            #pragma unroll
            for (int kk = 0; kk < 4; ++kk) {
                const float wk = (&w.x)[kk];
                #pragma unroll
                for (int m = 0; m < M; ++m)
                    ne[m] = fmaf(bcast(avg[m], k4 + kk), wk, ne[m]);
            }
        }
        #pragma unroll
        for (int m = 0; m < M; ++m) ne[m] = fmaxf(ne[m], 0.0f);

        // ---- xf = relu([x, ne] @ W_fus + b_fus) ----
        float xf[M];
        #pragma unroll
        for (int m = 0; m < M; ++m) xf[m] = s_b[64 + lane];
        #pragma unroll 4
        for (int k4 = 0; k4 < 64; k4 += 4) {
            const float4 w = *(const float4*)&s_fus[lane * SF + k4];
            #pragma unroll
            for (int kk = 0; kk < 4; ++kk) {
                const float wk = (&w.x)[kk];
                #pragma unroll
                for (int m = 0; m < M; ++m)
                    xf[m] = fmaf(bcast(xv[m], k4 + kk), wk, xf[m]);
            }
        }
        #pragma unroll 4
        for (int k4 = 0; k4 < 64; k4 += 4) {
            const float4 w = *(const float4*)&s_fus[lane * SF + 64 + k4];
            #pragma unroll
            for (int kk = 0; kk < 4; ++kk) {
                const float wk = (&w.x)[kk];
                #pragma unroll
                for (int m = 0; m < M; ++m)
                    xf[m] = fmaf(bcast(ne[m], k4 + kk), wk, xf[m]);
            }
        }
        #pragma unroll
        for (int m = 0; m < M; ++m) xf[m] = fmaxf(xf[m], 0.0f);

        // ---- h1 = relu(xf @ W1 + b1) ----
        float h1[M];
        #pragma unroll
        for (int m = 0; m < M; ++m) h1[m] = s_b[128 + lane];
        #pragma unroll 4
        for (int k4 = 0; k4 < 64; k4 += 4) {
            const float4 w = *(const float4*)&s_w1[lane * SA + k4];
            #pragma unroll
            for (int kk = 0; kk < 4; ++kk) {
                const float wk = (&w.x)[kk];
                #pragma unroll
                for (int m = 0; m < M; ++m)
                    h1[m] = fmaf(bcast(xf[m], k4 + kk), wk, h1[m]);
            }
        }
        #pragma unroll
        for (int m = 0; m < M; ++m) h1[m] = fmaxf(h1[m], 0.0f);

        // ---- mu, logvar ----
        float mu[M], lv[M];
        #pragma unroll
        for (int m = 0; m < M; ++m) { mu[m] = s_b[192 + j]; lv[m] = s_b[208 + j]; }
        #pragma unroll 4
        for (int k4 = 0; k4 < 64; k4 += 4) {
            const float4 w1v = *(const float4*)&s_w21[j * SA + k4];
            const float4 w2v = *(const float4*)&s_w22[j * SA + k4];
            #pragma unroll
            for (int kk = 0; kk < 4; ++kk) {
                const float wa = (&w1v.x)[kk];
                const float wb = (&w2v.x)[kk];
                #pragma unroll
                for (int m = 0; m < M; ++m) {
                    const float a = bcast(h1[m], k4 + kk);
                    mu[m] = fmaf(a, wa, mu[m]);
                    lv[m] = fmaf(a, wb, lv[m]);
                }
            }
        }

        // ---- z = mu + eps * exp(0.5*logvar) ----
        float z[M];
        #pragma unroll
        for (int m = 0; m < M; ++m)
            z[m] = mu[m] + eps[(long)(base + m) * 16 + j] * __expf(0.5f * lv[m]);

        // ---- h3 = relu(z @ W3 + b3); z_k lives in lane k (k<16) ----
        float h3[M];
        #pragma unroll
        for (int m = 0; m < M; ++m) h3[m] = s_b[224 + lane];
        #pragma unroll
        for (int k4 = 0; k4 < 16; k4 += 4) {
            const float4 w = *(const float4*)&s_w3[lane * S3 + k4];
            #pragma unroll
            for (int kk = 0; kk < 4; ++kk) {
                const float wk = (&w.x)[kk];
                #pragma unroll
                for (int m = 0; m < M; ++m)
                    h3[m] = fmaf(bcast(z[m], k4 + kk), wk, h3[m]);
            }
        }
        #pragma unroll
        for (int m = 0; m < M; ++m) h3[m] = fmaxf(h3[m], 0.0f);

        // ---- recon = sigmoid(h3 @ W4 + b4) ----
        float pre[M];
        #pragma unroll
        for (int m = 0; m < M; ++m) pre[m] = s_b[288 + lane];
        #pragma unroll 4
        for (int k4 = 0; k4 < 64; k4 += 4) {
            const float4 w = *(const float4*)&s_w4[lane * SA + k4];
            #pragma unroll
            for (int kk = 0; kk < 4; ++kk) {
                const float wk = (&w.x)[kk];
                #pragma unroll
                for (int m = 0; m < M; ++m)
                    pre[m] = fmaf(bcast(h3[m], k4 + kk), wk, pre[m]);
            }
        }

        // ---- outputs: recon [N,64] | mu [N,16] | logvar [N,16] ----
        #pragma unroll
        for (int m = 0; m < M; ++m) {
            const int node = base + m;
            out[(long)node * 64 + lane] = 1.0f / (1.0f + __expf(-pre[m]));
            if (lane < 16) {
                out[(long)N_NODES * 64 + (long)node * 16 + j] = mu[m];
                out[(long)N_NODES * 64 + (long)N_NODES * 16 + (long)node * 16 + j] = lv[m];
            }
        }
    }
}

extern "C" void kernel_launch(void* const* d_in, const int* in_sizes, int n_in,
                              void* d_out, int out_size, void* d_ws, size_t ws_size,
                              hipStream_t stream) {
    const float* x        = (const float*)d_in[0];
    const int*   edge_src = (const int*)  d_in[1];
    const int*   edge_dst = (const int*)  d_in[2];
    const float* eps      = (const float*)d_in[3];
    const float* W_agg    = (const float*)d_in[4];
    const float* b_agg    = (const float*)d_in[5];
    const float* W_fus    = (const float*)d_in[6];
    const float* b_fus    = (const float*)d_in[7];
    const float* W1       = (const float*)d_in[8];
    const float* b1       = (const float*)d_in[9];
    const float* W21      = (const float*)d_in[10];
    const float* b21      = (const float*)d_in[11];
    const float* W22      = (const float*)d_in[12];
    const float* b22      = (const float*)d_in[13];
    const float* W3       = (const float*)d_in[14];
    const float* b3       = (const float*)d_in[15];
    const float* W4       = (const float*)d_in[16];
    const float* b4       = (const float*)d_in[17];
    float* out = (float*)d_out;

    const int grid = 256;   // 1 block/CU (99 KB LDS), 16 waves each, grid-stride

    if (ws_size >= (size_t)(N_NODES + 1) * sizeof(int)) {
        int* row_start = (int*)d_ws;
        build_row_start<<<(E_EDGES + 255) / 256, 256, 0, stream>>>(edge_dst, row_start);
        vae_fused<true><<<grid, 1024, 0, stream>>>(x, edge_src, edge_dst, eps,
                                                   W_agg, b_agg, W_fus, b_fus,
                                                   W1, b1, W21, b21, W22, b22,
                                                   W3, b3, W4, b4, row_start, out);
    } else {
        vae_fused<false><<<grid, 1024, 0, stream>>>(x, edge_src, edge_dst, eps,
                                                    W_agg, b_agg, W_fus, b_fus,
                                                    W1, b1, W21, b21, W22, b22,
                                                    W3, b3, W4, b4, (const int*)nullptr, out);
    }
}

// Round 4
// 264.509 us; speedup vs baseline: 3.7923x; 1.2219x over previous
//
#include <hip/hip_runtime.h>
#include <math.h>

#define N_NODES 100000
#define E_EDGES 800000
#define NT 16                 // nodes per tile (one wave per tile)
#define NTILES (N_NODES / NT) // 6250
#define OFF_MU 6400000L
#define OFF_LV 8000000L

typedef __attribute__((ext_vector_type(8))) short short8;
typedef __attribute__((ext_vector_type(4))) float f32x4;
typedef __attribute__((ext_vector_type(4))) float float4v;

// weight fragment regions (in halves; each frag = 64 lanes * 8 halves = 512)
#define SW_AGG 0
#define SW_FUS 8192
#define SW_W1  24576
#define SW_W2  32768
#define SW_W3  36864
#define SW_W4  40960
#define SW_TOT 49152

__global__ void build_row_start(const int* __restrict__ edge_dst,
                                int* __restrict__ row_start) {
    int e = blockIdx.x * blockDim.x + threadIdx.x;
    if (e >= E_EDGES) return;
    int d = edge_dst[e];
    int dprev = (e == 0) ? -1 : edge_dst[e - 1];
    for (int n = dprev + 1; n <= d; ++n) row_start[n] = e;
    if (e == E_EDGES - 1) {
        for (int n = d + 1; n <= N_NODES; ++n) row_start[n] = E_EDGES;
    }
}

__device__ __forceinline__ unsigned short f2bf(float f) {
    unsigned u = __float_as_uint(f);
    unsigned r = u + 0x7FFFu + ((u >> 16) & 1u);
    return (unsigned short)(r >> 16);
}
__device__ __forceinline__ float bf2f(unsigned short h) {
    return __uint_as_float(((unsigned)h) << 16);
}
__device__ __forceinline__ void split8(const float* v, short8& hi, short8& lo) {
    #pragma unroll
    for (int i = 0; i < 8; ++i) {
        unsigned short h = f2bf(v[i]);
        hi[i] = (short)h;
        lo[i] = (short)f2bf(v[i] - bf2f(h));
    }
}

// XOR-swizzled activation tile address (16 rows x 64 f32 per wave)
__device__ __forceinline__ int actaddr(int row, int col) {
    return row * 64 + ((((col >> 2)) ^ (row & 15)) << 2) + (col & 3);
}

// stage one weight matrix into LDS as bf16 hi/lo B-fragments
__device__ void stage_w(const float* __restrict__ W, int Ksrc, int NC,
                        int NKT, int NJT_local, int jt_off, int NF_tot,
                        int rb, short* sw, int tid) {
    const int tot = NJT_local * NKT * 64;
    for (int s = tid; s < tot; s += 512) {
        int f = s >> 6, l = s & 63;
        int jtl = f / NKT, kt = f - jtl * NKT;
        int col = jtl * 16 + (l & 15);
        int k0 = kt * 32 + ((l >> 4) << 3);
        float v[8];
        #pragma unroll
        for (int i = 0; i < 8; ++i)
            v[i] = (k0 + i < Ksrc) ? W[(k0 + i) * NC + col] : 0.0f;
        short8 hi, lo; split8(v, hi, lo);
        int fg = (jt_off + jtl) * NKT + kt;
        *(short8*)&sw[rb + fg * 512 + l * 8] = hi;
        *(short8*)&sw[rb + (NF_tot + fg) * 512 + l * 8] = lo;
    }
}

template<int NKT>
__device__ __forceinline__ void frags_from_act(const float* actw, int lane,
                                               short8* hi, short8* lo) {
    const int row = lane & 15, ko = (lane >> 4) * 8;
    #pragma unroll
    for (int kt = 0; kt < NKT; ++kt) {
        float v[8];
        *(float4v*)&v[0] = *(const float4v*)&actw[actaddr(row, kt * 32 + ko)];
        *(float4v*)&v[4] = *(const float4v*)&actw[actaddr(row, kt * 32 + ko + 4)];
        split8(v, hi[kt], lo[kt]);
    }
}

template<int NJT, int NKT>
__device__ __forceinline__ void gemm_frag(const short8* ahi, const short8* alo,
                                          const short* sw, int rb,
                                          const float* bj, f32x4* c, int lane) {
    #pragma unroll
    for (int jt = 0; jt < NJT; ++jt) {
        f32x4 acc = { bj[jt], bj[jt], bj[jt], bj[jt] };
        #pragma unroll
        for (int kt = 0; kt < NKT; ++kt) {
            const short8 bhi = *(const short8*)&sw[rb + (jt * NKT + kt) * 512 + lane * 8];
            const short8 blo = *(const short8*)&sw[rb + (NJT * NKT + jt * NKT + kt) * 512 + lane * 8];
            acc = __builtin_amdgcn_mfma_f32_16x16x32_bf16(ahi[kt], bhi, acc, 0, 0, 0);
            acc = __builtin_amdgcn_mfma_f32_16x16x32_bf16(alo[kt], bhi, acc, 0, 0, 0);
            acc = __builtin_amdgcn_mfma_f32_16x16x32_bf16(ahi[kt], blo, acc, 0, 0, 0);
        }
        c[jt] = acc;
    }
}

__device__ __forceinline__ void write_act(float* actw, const f32x4* c, int lane) {
    const int g = lane >> 4, col0 = lane & 15;
    #pragma unroll
    for (int jt = 0; jt < 4; ++jt)
        #pragma unroll
        for (int r = 0; r < 4; ++r)
            actw[actaddr(g * 4 + r, jt * 16 + col0)] = fmaxf(c[jt][r], 0.0f);
}

__global__ __launch_bounds__(512) void vae_mfma(
    const float* __restrict__ x,
    const int* __restrict__ edge_src,
    const float* __restrict__ eps,
    const float* __restrict__ W_agg, const float* __restrict__ b_agg,
    const float* __restrict__ W_fus, const float* __restrict__ b_fus,
    const float* __restrict__ W1,  const float* __restrict__ b1,
    const float* __restrict__ W21, const float* __restrict__ b21,
    const float* __restrict__ W22, const float* __restrict__ b22,
    const float* __restrict__ W3,  const float* __restrict__ b3,
    const float* __restrict__ W4,  const float* __restrict__ b4,
    const int* __restrict__ row_start,
    float* __restrict__ out)
{
    __shared__ __align__(16) short s_w[SW_TOT];     // 96 KB
    __shared__ __align__(16) float s_act[8 * 1024]; // 32 KB

    const int tid = threadIdx.x;

    // ---- stage all weights as bf16 hi/lo fragments ----
    stage_w(W_agg, 64, 64, 2, 4, 0,  8, SW_AGG, s_w, tid);
    stage_w(W_fus, 128, 64, 4, 4, 0, 16, SW_FUS, s_w, tid);
    stage_w(W1,   64, 64, 2, 4, 0,  8, SW_W1,  s_w, tid);
    stage_w(W21,  64, 16, 2, 1, 0,  4, SW_W2,  s_w, tid);
    stage_w(W22,  64, 16, 2, 1, 1,  4, SW_W2,  s_w, tid);
    stage_w(W3,   16, 64, 1, 4, 0,  4, SW_W3,  s_w, tid);
    stage_w(W4,   64, 64, 2, 4, 0,  8, SW_W4,  s_w, tid);
    __syncthreads();

    const int lane = tid & 63;
    const int wid  = tid >> 6;
    float* actw = s_act + wid * 1024;
    const int gw = blockIdx.x * 8 + wid;
    const int nwaves = gridDim.x * 8;
    const int cj = lane & 15, g = lane >> 4;

    // ---- per-lane bias registers ----
    float bja[4], bjf[4], bj1[4], bj2[2], bj3[4], bj4[4];
    #pragma unroll
    for (int jt = 0; jt < 4; ++jt) {
        bja[jt] = b_agg[jt * 16 + cj];
        bjf[jt] = b_fus[jt * 16 + cj];
        bj1[jt] = b1[jt * 16 + cj];
        bj3[jt] = b3[jt * 16 + cj];
        bj4[jt] = b4[jt * 16 + cj];
    }
    bj2[0] = b21[cj];
    bj2[1] = b22[cj];

    for (int t = gw; t < NTILES; t += nwaves) {
        const int base = t * NT;

        // ---- gather: segment mean into act tile ----
        int idx = base + (lane < 17 ? lane : 16);
        int rsv = row_start[idx];
        for (int n = 0; n < NT; ++n) {
            int e0 = __builtin_amdgcn_readlane(rsv, n);
            int e1 = __builtin_amdgcn_readlane(rsv, n + 1);
            float sum = 0.0f;
            for (int e = e0; e < e1; ++e)
                sum += x[(long)edge_src[e] * 64 + lane];
            actw[actaddr(n, lane)] = sum / fmaxf((float)(e1 - e0), 1.0f);
        }

        short8 ahi[4], alo[4];
        f32x4 c4[4];

        // ---- ne = relu(avg @ W_agg + b_agg) ----
        frags_from_act<2>(actw, lane, ahi, alo);
        gemm_frag<4, 2>(ahi, alo, s_w, SW_AGG, bja, c4, lane);
        write_act(actw, c4, lane);                 // ne

        // ---- xf = relu([x, ne] @ W_fus + b_fus) ----
        {
            const int row = lane & 15, ko = (lane >> 4) * 8;
            const float* xrow = x + (long)(base + row) * 64;
            float v[8];
            *(float4v*)&v[0] = *(const float4v*)&xrow[ko];
            *(float4v*)&v[4] = *(const float4v*)&xrow[ko + 4];
            split8(v, ahi[0], alo[0]);
            *(float4v*)&v[0] = *(const float4v*)&xrow[32 + ko];
            *(float4v*)&v[4] = *(const float4v*)&xrow[32 + ko + 4];
            split8(v, ahi[1], alo[1]);
        }
        frags_from_act<2>(actw, lane, ahi + 2, alo + 2);   // ne part
        gemm_frag<4, 4>(ahi, alo, s_w, SW_FUS, bjf, c4, lane);
        write_act(actw, c4, lane);                 // xf

        // ---- h1 = relu(xf @ W1 + b1) ----
        frags_from_act<2>(actw, lane, ahi, alo);
        gemm_frag<4, 2>(ahi, alo, s_w, SW_W1, bj1, c4, lane);
        write_act(actw, c4, lane);                 // h1

        // ---- mu / logvar (combined 64x32 GEMM: jt0=mu, jt1=lv) ----
        frags_from_act<2>(actw, lane, ahi, alo);
        f32x4 c2[2];
        gemm_frag<2, 2>(ahi, alo, s_w, SW_W2, bj2, c2, lane);

        // ---- store mu/lv; z = mu + eps*exp(0.5*lv) ----
        float z4[4];
        #pragma unroll
        for (int r = 0; r < 4; ++r) {
            const long node = base + g * 4 + r;
            out[OFF_MU + node * 16 + cj] = c2[0][r];
            out[OFF_LV + node * 16 + cj] = c2[1][r];
            z4[r] = c2[0][r] + eps[node * 16 + cj] * __expf(0.5f * c2[1][r]);
        }

        // ---- h3 = relu(z @ W3 + b3), K padded to 32 ----
        #pragma unroll
        for (int r = 0; r < 4; ++r)
            actw[actaddr(g * 4 + r, cj)] = z4[r];
        {
            short8 zh = {0,0,0,0,0,0,0,0}, zl = {0,0,0,0,0,0,0,0};
            if (lane < 32) {
                float v[8];
                const int row = lane & 15, ko = (lane >> 4) * 8;  // 0 or 8
                *(float4v*)&v[0] = *(const float4v*)&actw[actaddr(row, ko)];
                *(float4v*)&v[4] = *(const float4v*)&actw[actaddr(row, ko + 4)];
                split8(v, zh, zl);
            }
            gemm_frag<4, 1>(&zh, &zl, s_w, SW_W3, bj3, c4, lane);
        }
        write_act(actw, c4, lane);                 // h3

        // ---- recon = sigmoid(h3 @ W4 + b4) ----
        frags_from_act<2>(actw, lane, ahi, alo);
        gemm_frag<4, 2>(ahi, alo, s_w, SW_W4, bj4, c4, lane);
        #pragma unroll
        for (int jt = 0; jt < 4; ++jt)
            #pragma unroll
            for (int r = 0; r < 4; ++r) {
                const float s = 1.0f / (1.0f + __expf(-c4[jt][r]));
                out[(long)(base + g * 4 + r) * 64 + jt * 16 + cj] = s;
            }
    }
}

extern "C" void kernel_launch(void* const* d_in, const int* in_sizes, int n_in,
                              void* d_out, int out_size, void* d_ws, size_t ws_size,
                              hipStream_t stream) {
    const float* x        = (const float*)d_in[0];
    const int*   edge_src = (const int*)  d_in[1];
    const int*   edge_dst = (const int*)  d_in[2];
    const float* eps      = (const float*)d_in[3];
    const float* W_agg    = (const float*)d_in[4];
    const float* b_agg    = (const float*)d_in[5];
    const float* W_fus    = (const float*)d_in[6];
    const float* b_fus    = (const float*)d_in[7];
    const float* W1       = (const float*)d_in[8];
    const float* b1       = (const float*)d_in[9];
    const float* W21      = (const float*)d_in[10];
    const float* b21      = (const float*)d_in[11];
    const float* W22      = (const float*)d_in[12];
    const float* b22      = (const float*)d_in[13];
    const float* W3       = (const float*)d_in[14];
    const float* b3       = (const float*)d_in[15];
    const float* W4       = (const float*)d_in[16];
    const float* b4       = (const float*)d_in[17];
    float* out = (float*)d_out;

    int* row_start = (int*)d_ws;   // (N+1) ints — ws proven >= this in r2/r3
    build_row_start<<<(E_EDGES + 255) / 256, 256, 0, stream>>>(edge_dst, row_start);
    vae_mfma<<<256, 512, 0, stream>>>(x, edge_src, eps,
                                      W_agg, b_agg, W_fus, b_fus,
                                      W1, b1, W21, b21, W22, b22,
                                      W3, b3, W4, b4, row_start, out);
}

// Round 5
// 135.811 us; speedup vs baseline: 7.3860x; 1.9476x over previous
//
#include <hip/hip_runtime.h>
#include <math.h>

#define N_NODES 100000
#define E_EDGES 800000
#define NT 16                 // nodes per tile (one wave per tile)
#define NTILES (N_NODES / NT) // 6250
#define OFF_MU 6400000L
#define OFF_LV 8000000L

typedef __attribute__((ext_vector_type(8))) short short8;
typedef __attribute__((ext_vector_type(4))) float f32x4;
typedef __attribute__((ext_vector_type(4))) float float4v;

// weight fragment regions (in halves; each frag = 64 lanes * 8 halves = 512)
#define SW_AGG 0
#define SW_FUS 8192
#define SW_W1  24576
#define SW_W2  32768
#define SW_W3  36864
#define SW_W4  40960
#define SW_TOT 49152

__global__ void build_row_start(const int* __restrict__ edge_dst,
                                int* __restrict__ row_start) {
    int e = blockIdx.x * blockDim.x + threadIdx.x;
    if (e >= E_EDGES) return;
    int d = edge_dst[e];
    int dprev = (e == 0) ? -1 : edge_dst[e - 1];
    for (int n = dprev + 1; n <= d; ++n) row_start[n] = e;
    if (e == E_EDGES - 1) {
        for (int n = d + 1; n <= N_NODES; ++n) row_start[n] = E_EDGES;
    }
}

__device__ __forceinline__ unsigned short f2bf(float f) {
    unsigned u = __float_as_uint(f);
    unsigned r = u + 0x7FFFu + ((u >> 16) & 1u);
    return (unsigned short)(r >> 16);
}
__device__ __forceinline__ float bf2f(unsigned short h) {
    return __uint_as_float(((unsigned)h) << 16);
}
__device__ __forceinline__ void split8(const float* v, short8& hi, short8& lo) {
    #pragma unroll
    for (int i = 0; i < 8; ++i) {
        unsigned short h = f2bf(v[i]);
        hi[i] = (short)h;
        lo[i] = (short)f2bf(v[i] - bf2f(h));
    }
}

// XOR-swizzled activation tile address (16 rows x 64 f32 per wave)
__device__ __forceinline__ int actaddr(int row, int col) {
    return row * 64 + ((((col >> 2)) ^ (row & 15)) << 2) + (col & 3);
}

// stage one weight matrix into LDS as bf16 hi/lo B-fragments
__device__ void stage_w(const float* __restrict__ W, int Ksrc, int NC,
                        int NKT, int NJT_local, int jt_off, int NF_tot,
                        int rb, short* sw, int tid) {
    const int tot = NJT_local * NKT * 64;
    for (int s = tid; s < tot; s += 512) {
        int f = s >> 6, l = s & 63;
        int jtl = f / NKT, kt = f - jtl * NKT;
        int col = jtl * 16 + (l & 15);
        int k0 = kt * 32 + ((l >> 4) << 3);
        float v[8];
        #pragma unroll
        for (int i = 0; i < 8; ++i)
            v[i] = (k0 + i < Ksrc) ? W[(k0 + i) * NC + col] : 0.0f;
        short8 hi, lo; split8(v, hi, lo);
        int fg = (jt_off + jtl) * NKT + kt;
        *(short8*)&sw[rb + fg * 512 + l * 8] = hi;
        *(short8*)&sw[rb + (NF_tot + fg) * 512 + l * 8] = lo;
    }
}

template<int NKT>
__device__ __forceinline__ void frags_from_act(const float* actw, int lane,
                                               short8* hi, short8* lo) {
    const int row = lane & 15, ko = (lane >> 4) * 8;
    #pragma unroll
    for (int kt = 0; kt < NKT; ++kt) {
        float v[8];
        *(float4v*)&v[0] = *(const float4v*)&actw[actaddr(row, kt * 32 + ko)];
        *(float4v*)&v[4] = *(const float4v*)&actw[actaddr(row, kt * 32 + ko + 4)];
        split8(v, hi[kt], lo[kt]);
    }
}

template<int NJT, int NKT>
__device__ __forceinline__ void gemm_frag(const short8* ahi, const short8* alo,
                                          const short* sw, int rb,
                                          const float* bj, f32x4* c, int lane) {
    #pragma unroll
    for (int jt = 0; jt < NJT; ++jt) {
        f32x4 acc = { bj[jt], bj[jt], bj[jt], bj[jt] };
        #pragma unroll
        for (int kt = 0; kt < NKT; ++kt) {
            const short8 bhi = *(const short8*)&sw[rb + (jt * NKT + kt) * 512 + lane * 8];
            const short8 blo = *(const short8*)&sw[rb + (NJT * NKT + jt * NKT + kt) * 512 + lane * 8];
            acc = __builtin_amdgcn_mfma_f32_16x16x32_bf16(ahi[kt], bhi, acc, 0, 0, 0);
            acc = __builtin_amdgcn_mfma_f32_16x16x32_bf16(alo[kt], bhi, acc, 0, 0, 0);
            acc = __builtin_amdgcn_mfma_f32_16x16x32_bf16(ahi[kt], blo, acc, 0, 0, 0);
        }
        c[jt] = acc;
    }
}

__device__ __forceinline__ void write_act(float* actw, const f32x4* c, int lane) {
    const int g = lane >> 4, col0 = lane & 15;
    #pragma unroll
    for (int jt = 0; jt < 4; ++jt)
        #pragma unroll
        for (int r = 0; r < 4; ++r)
            actw[actaddr(g * 4 + r, jt * 16 + col0)] = fmaxf(c[jt][r], 0.0f);
}

// edge index for tile-local edge te: from preloaded lane-parallel regs (<192)
// or direct load (overflow, ~never)
__device__ __forceinline__ int get_idx(int te, int iv0, int iv1, int iv2,
                                       const int* __restrict__ edge_src, int E0) {
    if (te < 192) {
        const int w = te >> 6, l = te & 63;
        const int v = (w == 0) ? iv0 : ((w == 1) ? iv1 : iv2);
        return __builtin_amdgcn_readlane(v, l);
    }
    return edge_src[E0 + te];
}

__global__ __launch_bounds__(512) void vae_mfma(
    const float* __restrict__ x,
    const int* __restrict__ edge_src,
    const float* __restrict__ eps,
    const float* __restrict__ W_agg, const float* __restrict__ b_agg,
    const float* __restrict__ W_fus, const float* __restrict__ b_fus,
    const float* __restrict__ W1,  const float* __restrict__ b1,
    const float* __restrict__ W21, const float* __restrict__ b21,
    const float* __restrict__ W22, const float* __restrict__ b22,
    const float* __restrict__ W3,  const float* __restrict__ b3,
    const float* __restrict__ W4,  const float* __restrict__ b4,
    const int* __restrict__ row_start,
    float* __restrict__ out)
{
    __shared__ __align__(16) short s_w[SW_TOT];     // 96 KB
    __shared__ __align__(16) float s_act[8 * 1024]; // 32 KB

    const int tid = threadIdx.x;

    // ---- stage all weights as bf16 hi/lo fragments ----
    stage_w(W_agg, 64, 64, 2, 4, 0,  8, SW_AGG, s_w, tid);
    stage_w(W_fus, 128, 64, 4, 4, 0, 16, SW_FUS, s_w, tid);
    stage_w(W1,   64, 64, 2, 4, 0,  8, SW_W1,  s_w, tid);
    stage_w(W21,  64, 16, 2, 1, 0,  4, SW_W2,  s_w, tid);
    stage_w(W22,  64, 16, 2, 1, 1,  4, SW_W2,  s_w, tid);
    stage_w(W3,   16, 64, 1, 4, 0,  4, SW_W3,  s_w, tid);
    stage_w(W4,   64, 64, 2, 4, 0,  8, SW_W4,  s_w, tid);
    __syncthreads();

    const int lane = tid & 63;
    const int wid  = tid >> 6;
    float* actw = s_act + wid * 1024;
    const int gw = blockIdx.x * 8 + wid;
    const int nwaves = gridDim.x * 8;
    const int cj = lane & 15, g = lane >> 4;

    // ---- per-lane bias registers ----
    float bja[4], bjf[4], bj1[4], bj2[2], bj3[4], bj4[4];
    #pragma unroll
    for (int jt = 0; jt < 4; ++jt) {
        bja[jt] = b_agg[jt * 16 + cj];
        bjf[jt] = b_fus[jt * 16 + cj];
        bj1[jt] = b1[jt * 16 + cj];
        bj3[jt] = b3[jt * 16 + cj];
        bj4[jt] = b4[jt * 16 + cj];
    }
    bj2[0] = b21[cj];
    bj2[1] = b22[cj];

    for (int t = gw; t < NTILES; t += nwaves) {
        const int base = t * NT;

        // ---- gather: segment mean into act tile (8-deep MLP) ----
        int idx17 = base + (lane < 17 ? lane : 16);
        int rsv = row_start[idx17];
        const int E0 = __builtin_amdgcn_readlane(rsv, 0);

        // lane-parallel preload of up to 192 tile edge indices
        int p0 = E0 + lane;       p0 = p0 < E_EDGES - 1 ? p0 : E_EDGES - 1;
        int p1 = E0 + 64 + lane;  p1 = p1 < E_EDGES - 1 ? p1 : E_EDGES - 1;
        int p2 = E0 + 128 + lane; p2 = p2 < E_EDGES - 1 ? p2 : E_EDGES - 1;
        const int iv0 = edge_src[p0];
        const int iv1 = edge_src[p1];
        const int iv2 = edge_src[p2];

        for (int n = 0; n < NT; ++n) {
            const int e0 = __builtin_amdgcn_readlane(rsv, n);
            const int e1 = __builtin_amdgcn_readlane(rsv, n + 1);
            float s0=0.f,s1=0.f,s2=0.f,s3=0.f,s4=0.f,s5=0.f,s6=0.f,s7=0.f;
            if (e1 > e0) {
                int e = e0;
                for (; e + 8 <= e1; e += 8) {
                    const int te = e - E0;
                    const int i0 = get_idx(te + 0, iv0, iv1, iv2, edge_src, E0);
                    const int i1 = get_idx(te + 1, iv0, iv1, iv2, edge_src, E0);
                    const int i2 = get_idx(te + 2, iv0, iv1, iv2, edge_src, E0);
                    const int i3 = get_idx(te + 3, iv0, iv1, iv2, edge_src, E0);
                    const int i4 = get_idx(te + 4, iv0, iv1, iv2, edge_src, E0);
                    const int i5 = get_idx(te + 5, iv0, iv1, iv2, edge_src, E0);
                    const int i6 = get_idx(te + 6, iv0, iv1, iv2, edge_src, E0);
                    const int i7 = get_idx(te + 7, iv0, iv1, iv2, edge_src, E0);
                    s0 += x[(long)i0 * 64 + lane];
                    s1 += x[(long)i1 * 64 + lane];
                    s2 += x[(long)i2 * 64 + lane];
                    s3 += x[(long)i3 * 64 + lane];
                    s4 += x[(long)i4 * 64 + lane];
                    s5 += x[(long)i5 * 64 + lane];
                    s6 += x[(long)i6 * 64 + lane];
                    s7 += x[(long)i7 * 64 + lane];
                }
                if (e < e1) {
                    // branchless masked tail batch of up to 7
                    #pragma unroll
                    for (int i = 0; i < 7; ++i) {
                        int ec = e + i;
                        const bool live = ec < e1;
                        ec = live ? ec : e0;
                        const int ix = get_idx(ec - E0, iv0, iv1, iv2, edge_src, E0);
                        float v = x[(long)ix * 64 + lane];
                        v = live ? v : 0.0f;
                        switch (i & 7) {
                            case 0: s0 += v; break; case 1: s1 += v; break;
                            case 2: s2 += v; break; case 3: s3 += v; break;
                            case 4: s4 += v; break; case 5: s5 += v; break;
                            case 6: s6 += v; break;
                        }
                    }
                }
            }
            const float sum = ((s0 + s1) + (s2 + s3)) + ((s4 + s5) + (s6 + s7));
            actw[actaddr(n, lane)] = sum / fmaxf((float)(e1 - e0), 1.0f);
        }

        short8 ahi[4], alo[4];
        f32x4 c4[4];

        // ---- ne = relu(avg @ W_agg + b_agg) ----
        frags_from_act<2>(actw, lane, ahi, alo);
        gemm_frag<4, 2>(ahi, alo, s_w, SW_AGG, bja, c4, lane);
        write_act(actw, c4, lane);                 // ne

        // ---- xf = relu([x, ne] @ W_fus + b_fus) ----
        {
            const int row = lane & 15, ko = (lane >> 4) * 8;
            const float* xrow = x + (long)(base + row) * 64;
            float v[8];
            *(float4v*)&v[0] = *(const float4v*)&xrow[ko];
            *(float4v*)&v[4] = *(const float4v*)&xrow[ko + 4];
            split8(v, ahi[0], alo[0]);
            *(float4v*)&v[0] = *(const float4v*)&xrow[32 + ko];
            *(float4v*)&v[4] = *(const float4v*)&xrow[32 + ko + 4];
            split8(v, ahi[1], alo[1]);
        }
        frags_from_act<2>(actw, lane, ahi + 2, alo + 2);   // ne part
        gemm_frag<4, 4>(ahi, alo, s_w, SW_FUS, bjf, c4, lane);
        write_act(actw, c4, lane);                 // xf

        // ---- h1 = relu(xf @ W1 + b1) ----
        frags_from_act<2>(actw, lane, ahi, alo);
        gemm_frag<4, 2>(ahi, alo, s_w, SW_W1, bj1, c4, lane);
        write_act(actw, c4, lane);                 // h1

        // ---- mu / logvar (combined 64x32 GEMM: jt0=mu, jt1=lv) ----
        frags_from_act<2>(actw, lane, ahi, alo);
        f32x4 c2[2];
        gemm_frag<2, 2>(ahi, alo, s_w, SW_W2, bj2, c2, lane);

        // ---- store mu/lv; z = mu + eps*exp(0.5*lv) ----
        float z4[4];
        #pragma unroll
        for (int r = 0; r < 4; ++r) {
            const long node = base + g * 4 + r;
            out[OFF_MU + node * 16 + cj] = c2[0][r];
            out[OFF_LV + node * 16 + cj] = c2[1][r];
            z4[r] = c2[0][r] + eps[node * 16 + cj] * __expf(0.5f * c2[1][r]);
        }

        // ---- h3 = relu(z @ W3 + b3), K padded to 32 ----
        #pragma unroll
        for (int r = 0; r < 4; ++r)
            actw[actaddr(g * 4 + r, cj)] = z4[r];
        {
            short8 zh = {0,0,0,0,0,0,0,0}, zl = {0,0,0,0,0,0,0,0};
            if (lane < 32) {
                float v[8];
                const int row = lane & 15, ko = (lane >> 4) * 8;  // 0 or 8
                *(float4v*)&v[0] = *(const float4v*)&actw[actaddr(row, ko)];
                *(float4v*)&v[4] = *(const float4v*)&actw[actaddr(row, ko + 4)];
                split8(v, zh, zl);
            }
            gemm_frag<4, 1>(&zh, &zl, s_w, SW_W3, bj3, c4, lane);
        }
        write_act(actw, c4, lane);                 // h3

        // ---- recon = sigmoid(h3 @ W4 + b4) ----
        frags_from_act<2>(actw, lane, ahi, alo);
        gemm_frag<4, 2>(ahi, alo, s_w, SW_W4, bj4, c4, lane);
        #pragma unroll
        for (int jt = 0; jt < 4; ++jt)
            #pragma unroll
            for (int r = 0; r < 4; ++r) {
                const float s = 1.0f / (1.0f + __expf(-c4[jt][r]));
                out[(long)(base + g * 4 + r) * 64 + jt * 16 + cj] = s;
            }
    }
}

extern "C" void kernel_launch(void* const* d_in, const int* in_sizes, int n_in,
                              void* d_out, int out_size, void* d_ws, size_t ws_size,
                              hipStream_t stream) {
    const float* x        = (const float*)d_in[0];
    const int*   edge_src = (const int*)  d_in[1];
    const int*   edge_dst = (const int*)  d_in[2];
    const float* eps      = (const float*)d_in[3];
    const float* W_agg    = (const float*)d_in[4];
    const float* b_agg    = (const float*)d_in[5];
    const float* W_fus    = (const float*)d_in[6];
    const float* b_fus    = (const float*)d_in[7];
    const float* W1       = (const float*)d_in[8];
    const float* b1       = (const float*)d_in[9];
    const float* W21      = (const float*)d_in[10];
    const float* b21      = (const float*)d_in[11];
    const float* W22      = (const float*)d_in[12];
    const float* b22      = (const float*)d_in[13];
    const float* W3       = (const float*)d_in[14];
    const float* b3       = (const float*)d_in[15];
    const float* W4       = (const float*)d_in[16];
    const float* b4       = (const float*)d_in[17];
    float* out = (float*)d_out;

    int* row_start = (int*)d_ws;
    build_row_start<<<(E_EDGES + 255) / 256, 256, 0, stream>>>(edge_dst, row_start);
    vae_mfma<<<256, 512, 0, stream>>>(x, edge_src, eps,
                                      W_agg, b_agg, W_fus, b_fus,
                                      W1, b1, W21, b21, W22, b22,
                                      W3, b3, W4, b4, row_start, out);
}